// Round 9
// baseline (710.480 us; speedup 1.0000x reference)
//
#include <hip/hip_runtime.h>
#include <hip/hip_bf16.h>
#include <cstdint>

#define DH 128   // hidden dim
#define NBS 64   // partition blocks for CSR counting sort (R21: 64 -> 128B runs/bucket)
#define NBK 1024 // max buckets (N <= 131072)

typedef __attribute__((ext_vector_type(8))) short short8;
typedef __attribute__((ext_vector_type(4))) float floatx4;
typedef __attribute__((ext_vector_type(2))) float floatx2;

__device__ __forceinline__ float bflo(unsigned u) { return __uint_as_float(u << 16); }
__device__ __forceinline__ float bfhi(unsigned u) { return __uint_as_float(u & 0xffff0000u); }

__device__ __forceinline__ unsigned pk_bf16(float a, float b) {
  return ((unsigned)__bfloat16_as_ushort(__float2bfloat16(b)) << 16)
       | (unsigned)__bfloat16_as_ushort(__float2bfloat16(a));
}

template<int CTRL>
__device__ __forceinline__ float dpp_add(float x) {
  int y = __builtin_amdgcn_update_dpp(0, __float_as_int(x), CTRL, 0xf, 0xf, true);
  return x + __int_as_float(y);
}

// ================= device bodies (shared by fused + standalone kernels) =========

// ---- csr_p1 body: histogram of dst>>7 per partition block ----
__device__ void csr_p1_body(int* cnt, const int* __restrict__ dst,
                            int* __restrict__ hist, int E, int chunk, int blk, int tid) {
  for (int c = tid; c < NBK; c += 256) cnt[c] = 0;
  __syncthreads();
  int base = blk * chunk;
  int end = base + chunk; if (end > E) end = E;
  for (int e = base + tid; e < end; e += 256) atomicAdd(&cnt[dst[e] >> 7], 1);
  __syncthreads();
  for (int c = tid; c < NBK; c += 256) hist[c * NBS + blk] = cnt[c];
}

// ---- pack_w body: one 32x32 tile (or bias block) of one layer ----
__device__ void pack_w_body(float* tileraw,
                            const float* __restrict__ Wq, const float* __restrict__ Wk,
                            const float* __restrict__ Wv, const float* __restrict__ Ws,
                            const float* __restrict__ bq, const float* __restrict__ bk,
                            const float* __restrict__ bv, const float* __restrict__ bs,
                            unsigned short* __restrict__ WT2l, float* __restrict__ bcl,
                            int bid, int tid) {
  if (bid == 64) {
    for (int c = tid; c < 512; c += 256) {
      int which = c >> 7, cc = c & 127;
      const float* b = (which == 0) ? bq : (which == 1) ? bk : (which == 2) ? bv : bs;
      bcl[c] = b[cc];
    }
    return;
  }
  float (*tile)[33] = (float(*)[33])tileraw;
  const int which = bid >> 4, kb = (bid >> 2) & 3, cb = bid & 3;
  const float* W = (which == 0) ? Wq : (which == 1) ? Wk : (which == 2) ? Wv : Ws;
  const int tx = tid & 31, ty = tid >> 5;   // ty 0..7
#pragma unroll
  for (int r = ty; r < 32; r += 8)
    tile[r][tx] = W[(kb * 32 + r) * 128 + cb * 32 + tx];
  __syncthreads();
  const int mt_sel = tid >> 7;            // 0..1
  const int s4 = (tid & 127) * 4;
  const int l16 = s4 >> 5;
  const int quad = (s4 >> 3) & 3;
  const int j0 = s4 & 7;
  const int cl = mt_sel * 16 + l16;
  const int kr = quad * 8 + j0;
  float f0 = tile[kr + 0][cl];
  float f1 = tile[kr + 1][cl];
  float f2 = tile[kr + 2][cl];
  float f3 = tile[kr + 3][cl];
  const int mt = which * 8 + cb * 2 + mt_sel;
  const int o = mt * 2048 + kb * 512 + l16 * 32 + quad * 8 + j0;
  uint2 w;
  w.x = pk_bf16(f0, f1);
  w.y = pk_bf16(f2, f3);
  *(uint2*)&WT2l[o] = w;
}

// ---- gemm body: 32-row tile, 4 waves, TRANSPOSED MFMA ----
template<int F32IN>
__device__ void gemm_body(short (*As)[132], const void* __restrict__ Xin,
                          const short* __restrict__ WT2, const float* __restrict__ bc,
                          unsigned int* __restrict__ qout, unsigned int* __restrict__ kvp,
                          unsigned int* __restrict__ xrout, int Nn, int row0, int tid) {
#pragma unroll
  for (int p = 0; p < 2; ++p) {
    int chunk = p * 256 + tid;    // 0..511
    int r = chunk >> 4, c8 = chunk & 15;
    int row = row0 + r; if (row >= Nn) row = Nn - 1;
    if (F32IN) {
      const float* xf = (const float*)Xin + (size_t)row * 128 + c8 * 8;
      float4 f0 = *(const float4*)xf;
      float4 f1 = *(const float4*)(xf + 4);
      int4 pk;
      ((unsigned*)&pk)[0] = pk_bf16(f0.x, f0.y);
      ((unsigned*)&pk)[1] = pk_bf16(f0.z, f0.w);
      ((unsigned*)&pk)[2] = pk_bf16(f1.x, f1.y);
      ((unsigned*)&pk)[3] = pk_bf16(f1.z, f1.w);
      *(int4*)&As[r][c8 * 8] = pk;
    } else {
      *(int4*)&As[r][c8 * 8] = *(const int4*)((const short*)Xin + (size_t)row * 128 + c8 * 8);
    }
  }
  __syncthreads();

  const int w = tid >> 6, lane = tid & 63, quad = lane >> 4, l16 = lane & 15;

  short8 xf[2][4];
#pragma unroll
  for (int nt = 0; nt < 2; ++nt)
#pragma unroll
    for (int kt = 0; kt < 4; ++kt)
      xf[nt][kt] = *(const short8*)&As[nt * 16 + l16][kt * 32 + quad * 8];

  const int fbase = l16 * 32 + quad * 8;

  if (w == 0 || w == 3) {
    unsigned int* outp = (w == 0) ? qout : xrout;
    const int mbase = (w == 0) ? 0 : 24;
#pragma unroll
    for (int i = 0; i < 8; ++i) {
      const int mt = mbase + i;
      short8 af[4];
#pragma unroll
      for (int kt = 0; kt < 4; ++kt)
        af[kt] = *(const short8*)&WT2[mt * 2048 + kt * 512 + fbase];
      float4 bias = *(const float4*)&bc[mt * 16 + quad * 4];
      const int wc = (i * 16 + quad * 4);
#pragma unroll
      for (int nt = 0; nt < 2; ++nt) {
        floatx4 acc = (floatx4){0.f, 0.f, 0.f, 0.f};
#pragma unroll
        for (int kt = 0; kt < 4; ++kt)
          acc = __builtin_amdgcn_mfma_f32_16x16x32_bf16(af[kt], xf[nt][kt], acc, 0, 0, 0);
        int node = row0 + nt * 16 + l16;
        if (node < Nn) {
          uint2 o;
          o.x = pk_bf16(acc[0] + bias.x, acc[1] + bias.y);
          o.y = pk_bf16(acc[2] + bias.z, acc[3] + bias.w);
          *(uint2*)&outp[(size_t)node * 64 + (wc >> 1)] = o;
        }
      }
    }
  } else {
    const int kb = 8 + (w - 1) * 4;
    const int vb = 16 + (w - 1) * 4;
#pragma unroll
    for (int i = 0; i < 4; ++i) {
      const int mk = kb + i, mv = vb + i;
      short8 afk[4], afv[4];
#pragma unroll
      for (int kt = 0; kt < 4; ++kt) {
        afk[kt] = *(const short8*)&WT2[mk * 2048 + kt * 512 + fbase];
        afv[kt] = *(const short8*)&WT2[mv * 2048 + kt * 512 + fbase];
      }
      float4 bk4 = *(const float4*)&bc[mk * 16 + quad * 4];
      float4 bv4 = *(const float4*)&bc[mv * 16 + quad * 4];
      const int krel = (w - 1) * 64 + i * 16 + quad * 4;
#pragma unroll
      for (int nt = 0; nt < 2; ++nt) {
        floatx4 ak = (floatx4){0.f, 0.f, 0.f, 0.f};
        floatx4 av = (floatx4){0.f, 0.f, 0.f, 0.f};
#pragma unroll
        for (int kt = 0; kt < 4; ++kt) {
          ak = __builtin_amdgcn_mfma_f32_16x16x32_bf16(afk[kt], xf[nt][kt], ak, 0, 0, 0);
          av = __builtin_amdgcn_mfma_f32_16x16x32_bf16(afv[kt], xf[nt][kt], av, 0, 0, 0);
        }
        int node = row0 + nt * 16 + l16;
        if (node < Nn) {
          int d0 = __builtin_amdgcn_cvt_pk_fp8_f32(ak[0] + bk4.x, ak[1] + bk4.y, 0, false);
          d0 = __builtin_amdgcn_cvt_pk_fp8_f32(av[0] + bv4.x, av[1] + bv4.y, d0, true);
          int d1 = __builtin_amdgcn_cvt_pk_fp8_f32(ak[2] + bk4.z, ak[3] + bk4.w, 0, false);
          d1 = __builtin_amdgcn_cvt_pk_fp8_f32(av[2] + bv4.z, av[3] + bv4.w, d1, true);
          uint2 o; o.x = (unsigned)d0; o.y = (unsigned)d1;
          *(uint2*)&kvp[(size_t)node * 64 + (krel >> 1)] = o;
        }
      }
    }
  }
}

// ---- csr_p3 body: scatter edges into dst-bucket partitions ----
__device__ void csr_p3_body(int* cur, const int* __restrict__ src, const int* __restrict__ dst,
                            const int* __restrict__ hist, const int* __restrict__ tstart,
                            int* __restrict__ part, int E, int chunk, int blk, int tid) {
  for (int c = tid; c < NBK; c += 256) cur[c] = hist[c * NBS + blk] + tstart[c];
  __syncthreads();
  int base = blk * chunk;
  int end = base + chunk; if (end > E) end = E;
  for (int e = base + tid; e < end; e += 256) {
    int d = dst[e];
    int b = d >> 7;
    int pos = atomicAdd(&cur[b], 1);     // LDS atomic
    part[pos] = (src[e] << 7) | (d & 127);
  }
}

// ================= kernels ======================================================

// ---- MEGA 1: csr_p1 | pack_w(4 layers) | goff — all independent ----
__global__ __launch_bounds__(256)
void fused_pre(const int* __restrict__ dst, int* __restrict__ hist, int E, int chunk,
               const int* __restrict__ batch, int* __restrict__ goff, int N, int G,
               const float* __restrict__ iWq, const float* __restrict__ iWk,
               const float* __restrict__ iWv, const float* __restrict__ iWs,
               const float* __restrict__ ibq, const float* __restrict__ ibk,
               const float* __restrict__ ibv, const float* __restrict__ ibs,
               const float* __restrict__ bWq, const float* __restrict__ bWk,
               const float* __restrict__ bWv, const float* __restrict__ bWs,
               const float* __restrict__ bbq, const float* __restrict__ bbk,
               const float* __restrict__ bbv, const float* __restrict__ bbs,
               __hip_bfloat16* __restrict__ WT2, float* __restrict__ bcat) {
  __shared__ int smem[1056];           // p1: cnt[1024]; pack: float tile[32][33]
  const int bid = blockIdx.x, tid = threadIdx.x;
  if (bid < NBS) {
    csr_p1_body(smem, dst, hist, E, chunk, bid, tid);
  } else if (bid < NBS + 260) {
    const int pb = bid - NBS;
    const int layer = pb / 65, sub = pb % 65;
    const float *Wq, *Wk, *Wv, *Ws, *bq, *bk, *bv, *bs;
    if (layer == 0) {
      Wq = iWq; Wk = iWk; Wv = iWv; Ws = iWs; bq = ibq; bk = ibk; bv = ibv; bs = ibs;
    } else {
      int m = layer - 1;
      Wq = bWq + (size_t)m * DH * DH; Wk = bWk + (size_t)m * DH * DH;
      Wv = bWv + (size_t)m * DH * DH; Ws = bWs + (size_t)m * DH * DH;
      bq = bbq + (size_t)m * DH; bk = bbk + (size_t)m * DH;
      bv = bbv + (size_t)m * DH; bs = bbs + (size_t)m * DH;
    }
    pack_w_body((float*)smem, Wq, Wk, Wv, Ws, bq, bk, bv, bs,
                (unsigned short*)WT2 + (size_t)layer * 65536, bcat + layer * 512, sub, tid);
  } else {
    int g = (bid - NBS - 260) * 256 + tid;
    if (g > G) return;
    if (g == G) { goff[G] = N; return; }
    int lo = 0, hi = N;
    while (lo < hi) { int mid = (lo + hi) >> 1; if (batch[mid] < g) lo = mid + 1; else hi = mid; }
    goff[g] = lo;
  }
}

// scan of 64 per-block offsets for each of 1024 buckets (one wave per bucket)
__global__ __launch_bounds__(256)
void csr_p2(int* __restrict__ hist, int* __restrict__ total) {
  int b = blockIdx.x * 4 + (threadIdx.x >> 6);   // bucket
  int lane = threadIdx.x & 63;
  int v = hist[b * NBS + lane];
  int t = v;
  for (int d = 1; d < 64; d <<= 1) {
    int y = __shfl_up(t, d);
    if (lane >= d) t += y;
  }
  hist[b * NBS + lane] = t - v;   // exclusive within bucket
  if (lane == 63) total[b] = t;
}

// fused single-block scan of total[NBK] -> tstart[NBK] (exclusive)
__global__ __launch_bounds__(1024)
void scan_tstart(const int* __restrict__ total, int* __restrict__ tstart) {
  __shared__ int sh[1024];
  int t = threadIdx.x;
  int v = total[t];
  sh[t] = v;
  __syncthreads();
  for (int d = 1; d < 1024; d <<= 1) {
    int x = (t >= d) ? sh[t - d] : 0;
    __syncthreads();
    sh[t] += x;
    __syncthreads();
  }
  tstart[t] = sh[t] - v;
}

// ---- MEGA 2: csr_p3 (blocks 0..NBS-1) | gemm layer-0 f32-in (rest) ----
__global__ __launch_bounds__(256, 4)
void fused_g0p3(const void* __restrict__ Xin, const short* __restrict__ WT2,
                const float* __restrict__ bc,
                unsigned int* __restrict__ qout, unsigned int* __restrict__ kvp,
                unsigned int* __restrict__ xrout, int Nn,
                const int* __restrict__ src, const int* __restrict__ dst,
                const int* __restrict__ hist, const int* __restrict__ tstart,
                int* __restrict__ part, int E, int chunk) {
  __shared__ int4 smem4[528];          // 8448 B: gemm As[32][132] shorts; p3 cur[1024] ints
  const int tid = threadIdx.x;
  if (blockIdx.x < NBS) {
    csr_p3_body((int*)smem4, src, dst, hist, tstart, part, E, chunk, blockIdx.x, tid);
  } else {
    gemm_body<1>((short(*)[132])smem4, Xin, WT2, bc, qout, kvp, xrout, Nn,
                 (blockIdx.x - NBS) * 32, tid);
  }
}

__global__ __launch_bounds__(256)
void csr_p4(const int* __restrict__ part, const int* __restrict__ tstart,
            const int* __restrict__ total, int2* __restrict__ offdeg,
            int* __restrict__ csr, int Nn) {
  __shared__ int lcnt[128], lscan[128], lcur[128];
  const int b = blockIdx.x, tid = threadIdx.x;
  const int p0 = tstart[b];
  const int m = total[b];
  if (tid < 128) lcnt[tid] = 0;
  __syncthreads();
  for (int k = tid; k < m; k += 256) atomicAdd(&lcnt[part[p0 + k] & 127], 1);
  __syncthreads();
  if (tid < 128) lscan[tid] = lcnt[tid];
  __syncthreads();
  for (int d = 1; d < 128; d <<= 1) {
    int v = 0;
    if (tid < 128 && tid >= d) v = lscan[tid - d];
    __syncthreads();
    if (tid < 128) lscan[tid] += v;
    __syncthreads();
  }
  if (tid < 128) {
    int ex = lscan[tid] - lcnt[tid];
    lcur[tid] = ex;
    int n = (b << 7) + tid;
    if (n < Nn) offdeg[n] = make_int2(p0 + ex, lcnt[tid]);
  }
  __syncthreads();
  for (int k = tid; k < m; k += 256) {
    int pk = part[p0 + k];
    int pos = p0 + atomicAdd(&lcur[pk & 127], 1);   // LDS atomic
    csr[pos] = pk >> 7;
  }
}

// ---- standalone gemm for layers 1..3 (bf16 input) ----
__global__ __launch_bounds__(256, 4)
void gemm_qkvs(const short* __restrict__ Xin, const short* __restrict__ WT2,
               const float* __restrict__ bc,
               unsigned int* __restrict__ qout, unsigned int* __restrict__ kvp,
               unsigned int* __restrict__ xrout, int Nn) {
  __shared__ int4 smem4[528];
  gemm_body<0>((short(*)[132])smem4, (const void*)Xin, WT2, bc, qout, kvp, xrout, Nn,
               blockIdx.x * 32, threadIdx.x);
}

// ---------------- attention: one WAVE per node, 16 lanes per edge (R16 proven) ---

__global__ __launch_bounds__(256)
void attn_kernel(unsigned int* __restrict__ q_h, const uint4* __restrict__ kvq,
                 const uint4* __restrict__ xr4, const int2* __restrict__ offdeg,
                 const int* __restrict__ csr, const float* __restrict__ Wb, int Nn) {
  int wv = __builtin_amdgcn_readfirstlane(threadIdx.x >> 6);
  int i = blockIdx.x * 4 + wv;
  if (i >= Nn) return;
  const int l = threadIdx.x & 63;
  const int j = l & 15;      // lane within edge-group: dims 8j..8j+7
  const int g = l >> 4;      // edge group 0..3

  const float QS = 0.17677669529663687f * 1.4426950408889634f;  // 1/sqrt(32)*log2e
  uint4 qw = ((const uint4*)q_h)[(size_t)i * 16 + j];
  int2 od = offdeg[i];
  float q0 = bflo(qw.x) * QS, q1 = bfhi(qw.x) * QS;
  float q2 = bflo(qw.y) * QS, q3 = bfhi(qw.y) * QS;
  float q4 = bflo(qw.z) * QS, q5 = bfhi(qw.z) * QS;
  float q6 = bflo(qw.w) * QS, q7 = bfhi(qw.w) * QS;

  const int e0 = od.x;
  const int dg = od.y;
  const int eend = e0 + dg;

  float denA = 0.f, denB = 0.f;
  float aA[8] = {0.f, 0.f, 0.f, 0.f, 0.f, 0.f, 0.f, 0.f};
  float aB[8] = {0.f, 0.f, 0.f, 0.f, 0.f, 0.f, 0.f, 0.f};

  auto comp = [&](const uint4& kv, bool valid, float& den, float (&a)[8]) {
    floatx2 k0 = __builtin_amdgcn_cvt_pk_f32_fp8((int)kv.x, false);
    floatx2 v0 = __builtin_amdgcn_cvt_pk_f32_fp8((int)kv.x, true);
    floatx2 k1 = __builtin_amdgcn_cvt_pk_f32_fp8((int)kv.y, false);
    floatx2 v1 = __builtin_amdgcn_cvt_pk_f32_fp8((int)kv.y, true);
    floatx2 k2 = __builtin_amdgcn_cvt_pk_f32_fp8((int)kv.z, false);
    floatx2 v2 = __builtin_amdgcn_cvt_pk_f32_fp8((int)kv.z, true);
    floatx2 k3 = __builtin_amdgcn_cvt_pk_f32_fp8((int)kv.w, false);
    floatx2 v3 = __builtin_amdgcn_cvt_pk_f32_fp8((int)kv.w, true);
    float d = q0 * k0.x + q1 * k0.y + q2 * k1.x + q3 * k1.y
            + q4 * k2.x + q5 * k2.y + q6 * k3.x + q7 * k3.y;
    d = dpp_add<0xB1>(d);        // quad_perm xor1
    d = dpp_add<0x4E>(d);        // quad_perm xor2 -> head dot in every lane of quad
    float p = valid ? exp2f(d) : 0.f;
    den += p;
    a[0] += p * v0.x; a[1] += p * v0.y; a[2] += p * v1.x; a[3] += p * v1.y;
    a[4] += p * v2.x; a[5] += p * v2.y; a[6] += p * v3.x; a[7] += p * v3.y;
  };

  for (int e = e0; e < eend; e += 64) {
    const int rem = eend - e;
    const int take = (rem < 64) ? rem : 64;          // chunk edge count (uniform)
    int il = e + l; if (il >= eend) il = eend - 1;
    const int sv = csr[il];                          // one coalesced load / 64 edges

    for (int b = 0; b < take; b += 16) {             // 16 edges (4 batches) in flight
      uint4 kv0, kv1, kv2, kv3;
      bool p0 = false, p1 = false, p2 = false, p3 = false;
      const int c0 = b + g, c1 = b + 4 + g, c2 = b + 8 + g, c3 = b + 12 + g;
      {
        p0 = c0 < take;
        int s = __shfl(sv, p0 ? c0 : 0);
        kv0 = kvq[(unsigned)((s << 4) | j)];
      }
      if (b + 4 < take) {
        p1 = c1 < take;
        int s = __shfl(sv, p1 ? c1 : 0);
        kv1 = kvq[(unsigned)((s << 4) | j)];
      }
      if (b + 8 < take) {
        p2 = c2 < take;
        int s = __shfl(sv, p2 ? c2 : 0);
        kv2 = kvq[(unsigned)((s << 4) | j)];
      }
      if (b + 12 < take) {
        p3 = c3 < take;
        int s = __shfl(sv, p3 ? c3 : 0);
        kv3 = kvq[(unsigned)((s << 4) | j)];
      }
      comp(kv0, p0, denA, aA);
      if (b + 4 < take)  comp(kv1, p1, denB, aB);
      if (b + 8 < take)  comp(kv2, p2, denA, aA);
      if (b + 12 < take) comp(kv3, p3, denB, aB);
    }
  }

  // issue epilogue loads early so they overlap the shuffle-merge chain
  uint4 xw = xr4[(size_t)i * 16 + j];
  float4 wo0 = *(const float4*)&Wb[8 * j];
  float4 wo1 = *(const float4*)&Wb[8 * j + 4];
  float4 wx0 = *(const float4*)&Wb[128 + 8 * j];
  float4 wx1 = *(const float4*)&Wb[128 + 8 * j + 4];
  float4 wd0 = *(const float4*)&Wb[256 + 8 * j];
  float4 wd1 = *(const float4*)&Wb[256 + 8 * j + 4];

  float den = denA + denB;
  float a0 = aA[0] + aB[0], a1 = aA[1] + aB[1], a2 = aA[2] + aB[2], a3 = aA[3] + aB[3];
  float a4 = aA[4] + aB[4], a5 = aA[5] + aB[5], a6 = aA[6] + aB[6], a7 = aA[7] + aB[7];

  // merge the 4 edge-groups (per node only; amortized over deg)
  den += __shfl_xor(den, 16); den += __shfl_xor(den, 32);
  a0 += __shfl_xor(a0, 16); a0 += __shfl_xor(a0, 32);
  a1 += __shfl_xor(a1, 16); a1 += __shfl_xor(a1, 32);
  a2 += __shfl_xor(a2, 16); a2 += __shfl_xor(a2, 32);
  a3 += __shfl_xor(a3, 16); a3 += __shfl_xor(a3, 32);
  a4 += __shfl_xor(a4, 16); a4 += __shfl_xor(a4, 32);
  a5 += __shfl_xor(a5, 16); a5 += __shfl_xor(a5, 32);
  a6 += __shfl_xor(a6, 16); a6 += __shfl_xor(a6, 32);
  a7 += __shfl_xor(a7, 16); a7 += __shfl_xor(a7, 32);

  float inv = 1.f / (den + 1e-16f);
  float o0 = a0 * inv, o1 = a1 * inv, o2 = a2 * inv, o3 = a3 * inv;
  float o4 = a4 * inv, o5 = a5 * inv, o6 = a6 * inv, o7 = a7 * inv;

  float x0 = bflo(xw.x), x1 = bfhi(xw.x);
  float x2 = bflo(xw.y), x3 = bfhi(xw.y);
  float x4 = bflo(xw.z), x5 = bfhi(xw.z);
  float x6 = bflo(xw.w), x7 = bfhi(xw.w);

  float c = o0 * wo0.x + o1 * wo0.y + o2 * wo0.z + o3 * wo0.w
          + o4 * wo1.x + o5 * wo1.y + o6 * wo1.z + o7 * wo1.w
          + x0 * wx0.x + x1 * wx0.y + x2 * wx0.z + x3 * wx0.w
          + x4 * wx1.x + x5 * wx1.y + x6 * wx1.z + x7 * wx1.w
          + (o0 - x0) * wd0.x + (o1 - x1) * wd0.y + (o2 - x2) * wd0.z + (o3 - x3) * wd0.w
          + (o4 - x4) * wd1.x + (o5 - x5) * wd1.y + (o6 - x6) * wd1.z + (o7 - x7) * wd1.w;
  // sum over the 16 lanes of each group — pure DPP
  c = dpp_add<0xB1>(c);    // xor1
  c = dpp_add<0x4E>(c);    // xor2
  c = dpp_add<0x141>(c);   // row_half_mirror: crosses quad within 8
  c = dpp_add<0x140>(c);   // row_mirror: crosses 8 within 16
  float beta = 1.f / (1.f + __expf(-c));

  if (g == 0) {
    float h0 = fmaxf(beta * x0 + (1.f - beta) * o0, 0.f);
    float h1 = fmaxf(beta * x1 + (1.f - beta) * o1, 0.f);
    float h2 = fmaxf(beta * x2 + (1.f - beta) * o2, 0.f);
    float h3 = fmaxf(beta * x3 + (1.f - beta) * o3, 0.f);
    float h4 = fmaxf(beta * x4 + (1.f - beta) * o4, 0.f);
    float h5 = fmaxf(beta * x5 + (1.f - beta) * o5, 0.f);
    float h6 = fmaxf(beta * x6 + (1.f - beta) * o6, 0.f);
    float h7 = fmaxf(beta * x7 + (1.f - beta) * o7, 0.f);
    uint4 hw;
    hw.x = pk_bf16(h0, h1);
    hw.y = pk_bf16(h2, h3);
    hw.z = pk_bf16(h4, h5);
    hw.w = pk_bf16(h6, h7);
    ((uint4*)q_h)[(size_t)i * 16 + j] = hw;
  }
}

// ---------------- fused mean-pool + MLP ----------------

__global__ __launch_bounds__(128)
void poolmlp_kernel(const unsigned short* __restrict__ h, const int* __restrict__ goff,
                    const float* __restrict__ W1, const float* __restrict__ b1,
                    const float* __restrict__ W2, const float* __restrict__ b2,
                    const float* __restrict__ W3, const float* __restrict__ b3,
                    float* __restrict__ out) {
  int g = blockIdx.x;
  int t = threadIdx.x;
  int n0 = goff[g], cnt = goff[g + 1] - n0;
  float s = 0.f;
  for (int n = n0; n < n0 + cnt; ++n) s += bflo(h[(size_t)n * 128 + t]);
  __shared__ float gv[128];
  __shared__ float t1[64];
  __shared__ float t2[32];
  gv[t] = s / fmaxf((float)cnt, 1.0f);
  __syncthreads();
  if (t < 64) {
    float a = b1[t];
    for (int k = 0; k < 128; ++k) a += gv[k] * W1[k * 64 + t];
    t1[t] = fmaxf(a, 0.f);
  }
  __syncthreads();
  if (t < 32) {
    float a = b2[t];
    for (int k = 0; k < 64; ++k) a += t1[k] * W2[k * 32 + t];
    t2[t] = fmaxf(a, 0.f);
  }
  __syncthreads();
  if (t == 0) {
    float a = b3[0];
    for (int k = 0; k < 32; ++k) a += t2[k] * W3[k];
    out[g] = 1.f / (1.f + __expf(-a));
  }
}

// ---------------- launch ----------------

extern "C" void kernel_launch(void* const* d_in, const int* in_sizes, int n_in,
                              void* d_out, int out_size, void* d_ws, size_t ws_size,
                              hipStream_t stream) {
  const float* x = (const float*)d_in[0];
  const int* edge_index = (const int*)d_in[1];
  const int* batch = (const int*)d_in[2];
  const int N = in_sizes[0] / DH;
  const int E = in_sizes[1] / 2;
  const int G = out_size;
  const int* src = edge_index;
  const int* dst = edge_index + E;

  const float* in_Wq = (const float*)d_in[3];
  const float* in_bq = (const float*)d_in[4];
  const float* in_Wk = (const float*)d_in[5];
  const float* in_bk = (const float*)d_in[6];
  const float* in_Wv = (const float*)d_in[7];
  const float* in_bv = (const float*)d_in[8];
  const float* in_Ws = (const float*)d_in[9];
  const float* in_bs = (const float*)d_in[10];
  const float* in_Wbeta = (const float*)d_in[11];
  const float* blk_Wq = (const float*)d_in[12];
  const float* blk_bq = (const float*)d_in[13];
  const float* blk_Wk = (const float*)d_in[14];
  const float* blk_bk = (const float*)d_in[15];
  const float* blk_Wv = (const float*)d_in[16];
  const float* blk_bv = (const float*)d_in[17];
  const float* blk_Ws = (const float*)d_in[18];
  const float* blk_bs = (const float*)d_in[19];
  const float* blk_Wbeta = (const float*)d_in[20];

  // workspace carve (256B aligned)
  char* p = (char*)d_ws;
  auto take = [&](size_t bytes) { char* r = p; p += (bytes + 255) & ~(size_t)255; return r; };
  __hip_bfloat16* h0 = (__hip_bfloat16*)take((size_t)N * DH * 2);
  __hip_bfloat16* h1 = (__hip_bfloat16*)take((size_t)N * DH * 2);
  unsigned char* kvp = (unsigned char*)take((size_t)N * 256);
  unsigned short* xr = (unsigned short*)take((size_t)N * DH * 2);
  __hip_bfloat16* WT2 = (__hip_bfloat16*)take((size_t)4 * 512 * DH * 2);
  float* bcat = (float*)take((size_t)4 * 512 * 4);
  int2* offdeg = (int2*)take((size_t)N * 8);
  int* csr    = (int*)take((size_t)E * 4);
  int* part   = (int*)take((size_t)E * 4);
  int* hist   = (int*)take((size_t)NBS * NBK * 4);
  int* total  = (int*)take(NBK * 4);
  int* tstart = (int*)take(NBK * 4);
  int* goff   = (int*)take((size_t)(G + 1) * 4);
  (void)n_in;
  if ((size_t)(p - (char*)d_ws) > ws_size) return;

  const int NBUCK = (N + 127) >> 7;
  const int chunk = (E + NBS - 1) / NBS;
  const int gblocks = (G + 256) / 256;

  // ---- MEGA 1: csr_p1 | pack_w(all layers) | goff ----
  fused_pre<<<NBS + 260 + gblocks, 256, 0, stream>>>(
      dst, hist, E, chunk, batch, goff, N, G,
      in_Wq, in_Wk, in_Wv, in_Ws, in_bq, in_bk, in_bv, in_bs,
      blk_Wq, blk_Wk, blk_Wv, blk_Ws, blk_bq, blk_bk, blk_bv, blk_bs,
      WT2, bcat);

  csr_p2<<<NBK / 4, 256, 0, stream>>>(hist, total);
  scan_tstart<<<1, 1024, 0, stream>>>(total, tstart);

  // ---- MEGA 2: csr_p3 (first NBS blocks) | gemm layer-0 ----
  fused_g0p3<<<NBS + (N + 31) / 32, 256, 0, stream>>>(
      (const void*)x, (const short*)WT2, bcat,
      (unsigned int*)h1, (unsigned int*)kvp, (unsigned int*)xr, N,
      src, dst, hist, tstart, part, E, chunk);

  csr_p4<<<NBUCK, 256, 0, stream>>>(part, tstart, total, offdeg, csr, N);

  // layer 0 attention (q in h1, h -> h1)
  attn_kernel<<<(N + 3) / 4, 256, 0, stream>>>((unsigned int*)h1, (const uint4*)kvp,
      (const uint4*)xr, offdeg, csr, in_Wbeta, N);

  for (int l = 1; l < 4; ++l) {
    const float* Wb = blk_Wbeta + (size_t)(l - 1) * 3 * DH;
    const short* WT2l = (const short*)WT2 + (size_t)l * 65536;
    const float* bcl = bcat + (size_t)l * 512;
    __hip_bfloat16* hin  = (l & 1) ? h1 : h0;   // layer1 reads h1, writes q to h0; etc.
    __hip_bfloat16* qbuf = (l & 1) ? h0 : h1;
    gemm_qkvs<<<(N + 31) / 32, 256, 0, stream>>>((const short*)hin, WT2l, bcl,
        (unsigned int*)qbuf, (unsigned int*)kvp, (unsigned int*)xr, N);
    attn_kernel<<<(N + 3) / 4, 256, 0, stream>>>((unsigned int*)qbuf, (const uint4*)kvp,
        (const uint4*)xr, offdeg, csr, Wb, N);
  }

  // after 4 layers h lives in h0 (layers wrote h1,h0,h1,h0)
  poolmlp_kernel<<<G, 128, 0, stream>>>((const unsigned short*)h0, goff,
      (const float*)d_in[21], (const float*)d_in[22],
      (const float*)d_in[23], (const float*)d_in[24],
      (const float*)d_in[25], (const float*)d_in[26],
      (float*)d_out);
}

// Round 10
// 647.759 us; speedup vs baseline: 1.0968x; 1.0968x over previous
//
#include <hip/hip_runtime.h>
#include <hip/hip_bf16.h>
#include <cstdint>

#define DH 128   // hidden dim
#define NB 256   // partition blocks for CSR counting sort (R22: reverted, 256 proven)
#define NBK 1024 // max buckets (N <= 131072)

typedef __attribute__((ext_vector_type(8))) short short8;
typedef __attribute__((ext_vector_type(4))) float floatx4;
typedef __attribute__((ext_vector_type(2))) float floatx2;

__device__ __forceinline__ float bflo(unsigned u) { return __uint_as_float(u << 16); }
__device__ __forceinline__ float bfhi(unsigned u) { return __uint_as_float(u & 0xffff0000u); }

__device__ __forceinline__ unsigned pk_bf16(float a, float b) {
  return ((unsigned)__bfloat16_as_ushort(__float2bfloat16(b)) << 16)
       | (unsigned)__bfloat16_as_ushort(__float2bfloat16(a));
}

template<int CTRL>
__device__ __forceinline__ float dpp_add(float x) {
  int y = __builtin_amdgcn_update_dpp(0, __float_as_int(x), CTRL, 0xf, 0xf, true);
  return x + __int_as_float(y);
}

// ================= device bodies (shared by fused + standalone kernels) =========

// ---- csr_p1 body: histogram of dst>>7 per partition block ----
__device__ void csr_p1_body(int* cnt, const int* __restrict__ dst,
                            int* __restrict__ hist, int E, int chunk, int blk, int tid) {
  for (int c = tid; c < NBK; c += 256) cnt[c] = 0;
  __syncthreads();
  int base = blk * chunk;
  int end = base + chunk; if (end > E) end = E;
  for (int e = base + tid; e < end; e += 256) atomicAdd(&cnt[dst[e] >> 7], 1);
  __syncthreads();
  for (int c = tid; c < NBK; c += 256) hist[c * NB + blk] = cnt[c];
}

// ---- pack_w body: one 32x32 tile (or bias block) of one layer ----
__device__ void pack_w_body(float* tileraw,
                            const float* __restrict__ Wq, const float* __restrict__ Wk,
                            const float* __restrict__ Wv, const float* __restrict__ Ws,
                            const float* __restrict__ bq, const float* __restrict__ bk,
                            const float* __restrict__ bv, const float* __restrict__ bs,
                            unsigned short* __restrict__ WT2l, float* __restrict__ bcl,
                            int bid, int tid) {
  if (bid == 64) {
    for (int c = tid; c < 512; c += 256) {
      int which = c >> 7, cc = c & 127;
      const float* b = (which == 0) ? bq : (which == 1) ? bk : (which == 2) ? bv : bs;
      bcl[c] = b[cc];
    }
    return;
  }
  float (*tile)[33] = (float(*)[33])tileraw;
  const int which = bid >> 4, kb = (bid >> 2) & 3, cb = bid & 3;
  const float* W = (which == 0) ? Wq : (which == 1) ? Wk : (which == 2) ? Wv : Ws;
  const int tx = tid & 31, ty = tid >> 5;   // ty 0..7
#pragma unroll
  for (int r = ty; r < 32; r += 8)
    tile[r][tx] = W[(kb * 32 + r) * 128 + cb * 32 + tx];
  __syncthreads();
  const int mt_sel = tid >> 7;            // 0..1
  const int s4 = (tid & 127) * 4;
  const int l16 = s4 >> 5;
  const int quad = (s4 >> 3) & 3;
  const int j0 = s4 & 7;
  const int cl = mt_sel * 16 + l16;
  const int kr = quad * 8 + j0;
  float f0 = tile[kr + 0][cl];
  float f1 = tile[kr + 1][cl];
  float f2 = tile[kr + 2][cl];
  float f3 = tile[kr + 3][cl];
  const int mt = which * 8 + cb * 2 + mt_sel;
  const int o = mt * 2048 + kb * 512 + l16 * 32 + quad * 8 + j0;
  uint2 w;
  w.x = pk_bf16(f0, f1);
  w.y = pk_bf16(f2, f3);
  *(uint2*)&WT2l[o] = w;
}

// ---- gemm body: 32-row tile, 4 waves, TRANSPOSED MFMA ----
// R22: manual 1-deep prefetch of next m-tile's weight fragments — forces
// load/compute overlap the compiler refused at VGPR=48 (R19/R20 evidence).
template<int F32IN>
__device__ void gemm_body(short (*As)[132], const void* __restrict__ Xin,
                          const short* __restrict__ WT2, const float* __restrict__ bc,
                          unsigned int* __restrict__ qout, unsigned int* __restrict__ kvp,
                          unsigned int* __restrict__ xrout, int Nn, int row0, int tid) {
#pragma unroll
  for (int p = 0; p < 2; ++p) {
    int chunk = p * 256 + tid;    // 0..511
    int r = chunk >> 4, c8 = chunk & 15;
    int row = row0 + r; if (row >= Nn) row = Nn - 1;
    if (F32IN) {
      const float* xf = (const float*)Xin + (size_t)row * 128 + c8 * 8;
      float4 f0 = *(const float4*)xf;
      float4 f1 = *(const float4*)(xf + 4);
      int4 pk;
      ((unsigned*)&pk)[0] = pk_bf16(f0.x, f0.y);
      ((unsigned*)&pk)[1] = pk_bf16(f0.z, f0.w);
      ((unsigned*)&pk)[2] = pk_bf16(f1.x, f1.y);
      ((unsigned*)&pk)[3] = pk_bf16(f1.z, f1.w);
      *(int4*)&As[r][c8 * 8] = pk;
    } else {
      *(int4*)&As[r][c8 * 8] = *(const int4*)((const short*)Xin + (size_t)row * 128 + c8 * 8);
    }
  }
  __syncthreads();

  const int w = tid >> 6, lane = tid & 63, quad = lane >> 4, l16 = lane & 15;

  short8 xf[2][4];
#pragma unroll
  for (int nt = 0; nt < 2; ++nt)
#pragma unroll
    for (int kt = 0; kt < 4; ++kt)
      xf[nt][kt] = *(const short8*)&As[nt * 16 + l16][kt * 32 + quad * 8];

  const int fbase = l16 * 32 + quad * 8;

  if (w == 0 || w == 3) {
    unsigned int* outp = (w == 0) ? qout : xrout;
    const int mbase = (w == 0) ? 0 : 24;
    short8 afc[4];
#pragma unroll
    for (int kt = 0; kt < 4; ++kt)
      afc[kt] = *(const short8*)&WT2[mbase * 2048 + kt * 512 + fbase];
#pragma unroll
    for (int i = 0; i < 8; ++i) {
      const int mt = mbase + i;
      short8 afn[4];
      if (i < 7) {
#pragma unroll
        for (int kt = 0; kt < 4; ++kt)
          afn[kt] = *(const short8*)&WT2[(mt + 1) * 2048 + kt * 512 + fbase];
      }
      float4 bias = *(const float4*)&bc[mt * 16 + quad * 4];
      const int wc = (i * 16 + quad * 4);
#pragma unroll
      for (int nt = 0; nt < 2; ++nt) {
        floatx4 acc = (floatx4){0.f, 0.f, 0.f, 0.f};
#pragma unroll
        for (int kt = 0; kt < 4; ++kt)
          acc = __builtin_amdgcn_mfma_f32_16x16x32_bf16(afc[kt], xf[nt][kt], acc, 0, 0, 0);
        int node = row0 + nt * 16 + l16;
        if (node < Nn) {
          uint2 o;
          o.x = pk_bf16(acc[0] + bias.x, acc[1] + bias.y);
          o.y = pk_bf16(acc[2] + bias.z, acc[3] + bias.w);
          *(uint2*)&outp[(size_t)node * 64 + (wc >> 1)] = o;
        }
      }
      if (i < 7) {
#pragma unroll
        for (int kt = 0; kt < 4; ++kt) afc[kt] = afn[kt];
      }
    }
  } else {
    const int kb = 8 + (w - 1) * 4;
    const int vb = 16 + (w - 1) * 4;
    short8 afkc[4], afvc[4];
#pragma unroll
    for (int kt = 0; kt < 4; ++kt) {
      afkc[kt] = *(const short8*)&WT2[kb * 2048 + kt * 512 + fbase];
      afvc[kt] = *(const short8*)&WT2[vb * 2048 + kt * 512 + fbase];
    }
#pragma unroll
    for (int i = 0; i < 4; ++i) {
      const int mk = kb + i, mv = vb + i;
      short8 afkn[4], afvn[4];
      if (i < 3) {
#pragma unroll
        for (int kt = 0; kt < 4; ++kt) {
          afkn[kt] = *(const short8*)&WT2[(mk + 1) * 2048 + kt * 512 + fbase];
          afvn[kt] = *(const short8*)&WT2[(mv + 1) * 2048 + kt * 512 + fbase];
        }
      }
      float4 bk4 = *(const float4*)&bc[mk * 16 + quad * 4];
      float4 bv4 = *(const float4*)&bc[mv * 16 + quad * 4];
      const int krel = (w - 1) * 64 + i * 16 + quad * 4;
#pragma unroll
      for (int nt = 0; nt < 2; ++nt) {
        floatx4 ak = (floatx4){0.f, 0.f, 0.f, 0.f};
        floatx4 av = (floatx4){0.f, 0.f, 0.f, 0.f};
#pragma unroll
        for (int kt = 0; kt < 4; ++kt) {
          ak = __builtin_amdgcn_mfma_f32_16x16x32_bf16(afkc[kt], xf[nt][kt], ak, 0, 0, 0);
          av = __builtin_amdgcn_mfma_f32_16x16x32_bf16(afvc[kt], xf[nt][kt], av, 0, 0, 0);
        }
        int node = row0 + nt * 16 + l16;
        if (node < Nn) {
          int d0 = __builtin_amdgcn_cvt_pk_fp8_f32(ak[0] + bk4.x, ak[1] + bk4.y, 0, false);
          d0 = __builtin_amdgcn_cvt_pk_fp8_f32(av[0] + bv4.x, av[1] + bv4.y, d0, true);
          int d1 = __builtin_amdgcn_cvt_pk_fp8_f32(ak[2] + bk4.z, ak[3] + bk4.w, 0, false);
          d1 = __builtin_amdgcn_cvt_pk_fp8_f32(av[2] + bv4.z, av[3] + bv4.w, d1, true);
          uint2 o; o.x = (unsigned)d0; o.y = (unsigned)d1;
          *(uint2*)&kvp[(size_t)node * 64 + (krel >> 1)] = o;
        }
      }
      if (i < 3) {
#pragma unroll
        for (int kt = 0; kt < 4; ++kt) { afkc[kt] = afkn[kt]; afvc[kt] = afvn[kt]; }
      }
    }
  }
}

// ---- csr_p3 body: scatter edges into dst-bucket partitions ----
__device__ void csr_p3_body(int* cur, const int* __restrict__ src, const int* __restrict__ dst,
                            const int* __restrict__ hist, const int* __restrict__ tstart,
                            int* __restrict__ part, int E, int chunk, int blk, int tid) {
  for (int c = tid; c < NBK; c += 256) cur[c] = hist[c * NB + blk] + tstart[c];
  __syncthreads();
  int base = blk * chunk;
  int end = base + chunk; if (end > E) end = E;
  for (int e = base + tid; e < end; e += 256) {
    int d = dst[e];
    int b = d >> 7;
    int pos = atomicAdd(&cur[b], 1);     // LDS atomic
    part[pos] = (src[e] << 7) | (d & 127);
  }
}

// ================= kernels ======================================================

// ---- MEGA 1: csr_p1 | pack_w(4 layers) | goff — all independent ----
__global__ __launch_bounds__(256)
void fused_pre(const int* __restrict__ dst, int* __restrict__ hist, int E, int chunk,
               const int* __restrict__ batch, int* __restrict__ goff, int N, int G,
               const float* __restrict__ iWq, const float* __restrict__ iWk,
               const float* __restrict__ iWv, const float* __restrict__ iWs,
               const float* __restrict__ ibq, const float* __restrict__ ibk,
               const float* __restrict__ ibv, const float* __restrict__ ibs,
               const float* __restrict__ bWq, const float* __restrict__ bWk,
               const float* __restrict__ bWv, const float* __restrict__ bWs,
               const float* __restrict__ bbq, const float* __restrict__ bbk,
               const float* __restrict__ bbv, const float* __restrict__ bbs,
               __hip_bfloat16* __restrict__ WT2, float* __restrict__ bcat) {
  __shared__ int smem[1056];           // p1: cnt[1024]; pack: float tile[32][33]
  const int bid = blockIdx.x, tid = threadIdx.x;
  if (bid < NB) {
    csr_p1_body(smem, dst, hist, E, chunk, bid, tid);
  } else if (bid < NB + 260) {
    const int pb = bid - NB;
    const int layer = pb / 65, sub = pb % 65;
    const float *Wq, *Wk, *Wv, *Ws, *bq, *bk, *bv, *bs;
    if (layer == 0) {
      Wq = iWq; Wk = iWk; Wv = iWv; Ws = iWs; bq = ibq; bk = ibk; bv = ibv; bs = ibs;
    } else {
      int m = layer - 1;
      Wq = bWq + (size_t)m * DH * DH; Wk = bWk + (size_t)m * DH * DH;
      Wv = bWv + (size_t)m * DH * DH; Ws = bWs + (size_t)m * DH * DH;
      bq = bbq + (size_t)m * DH; bk = bbk + (size_t)m * DH;
      bv = bbv + (size_t)m * DH; bs = bbs + (size_t)m * DH;
    }
    pack_w_body((float*)smem, Wq, Wk, Wv, Ws, bq, bk, bv, bs,
                (unsigned short*)WT2 + (size_t)layer * 65536, bcat + layer * 512, sub, tid);
  } else {
    int g = (bid - NB - 260) * 256 + tid;
    if (g > G) return;
    if (g == G) { goff[G] = N; return; }
    int lo = 0, hi = N;
    while (lo < hi) { int mid = (lo + hi) >> 1; if (batch[mid] < g) lo = mid + 1; else hi = mid; }
    goff[g] = lo;
  }
}

__global__ __launch_bounds__(256)
void csr_p2(int* __restrict__ hist, int* __restrict__ total) {
  int b = blockIdx.x * 4 + (threadIdx.x >> 6);   // bucket
  int lane = threadIdx.x & 63;
  int4 v = *(int4*)&hist[b * NB + lane * 4];
  int s0 = v.x;
  int s1 = s0 + v.y;
  int s2 = s1 + v.z;
  int s3 = s2 + v.w;
  int t = s3;
  for (int d = 1; d < 64; d <<= 1) {
    int y = __shfl_up(t, d);
    if (lane >= d) t += y;
  }
  int excl = t - s3;
  int4 o;
  o.x = excl; o.y = excl + s0; o.z = excl + s1; o.w = excl + s2;
  *(int4*)&hist[b * NB + lane * 4] = o;
  if (lane == 63) total[b] = t;
}

// fused single-block scan of total[NBK] -> tstart[NBK] (exclusive)
__global__ __launch_bounds__(1024)
void scan_tstart(const int* __restrict__ total, int* __restrict__ tstart) {
  __shared__ int sh[1024];
  int t = threadIdx.x;
  int v = total[t];
  sh[t] = v;
  __syncthreads();
  for (int d = 1; d < 1024; d <<= 1) {
    int x = (t >= d) ? sh[t - d] : 0;
    __syncthreads();
    sh[t] += x;
    __syncthreads();
  }
  tstart[t] = sh[t] - v;
}

// ---- MEGA 2: csr_p3 (blocks 0..NB-1) | gemm layer-0 f32-in (rest) ----
__global__ __launch_bounds__(256, 4)
void fused_g0p3(const void* __restrict__ Xin, const short* __restrict__ WT2,
                const float* __restrict__ bc,
                unsigned int* __restrict__ qout, unsigned int* __restrict__ kvp,
                unsigned int* __restrict__ xrout, int Nn,
                const int* __restrict__ src, const int* __restrict__ dst,
                const int* __restrict__ hist, const int* __restrict__ tstart,
                int* __restrict__ part, int E, int chunk) {
  __shared__ int4 smem4[528];          // 8448 B: gemm As[32][132] shorts; p3 cur[1024] ints
  const int tid = threadIdx.x;
  if (blockIdx.x < NB) {
    csr_p3_body((int*)smem4, src, dst, hist, tstart, part, E, chunk, blockIdx.x, tid);
  } else {
    gemm_body<1>((short(*)[132])smem4, Xin, WT2, bc, qout, kvp, xrout, Nn,
                 (blockIdx.x - NB) * 32, tid);
  }
}

__global__ __launch_bounds__(256)
void csr_p4(const int* __restrict__ part, const int* __restrict__ tstart,
            const int* __restrict__ total, int2* __restrict__ offdeg,
            int* __restrict__ csr, int Nn) {
  __shared__ int lcnt[128], lscan[128], lcur[128];
  const int b = blockIdx.x, tid = threadIdx.x;
  const int p0 = tstart[b];
  const int m = total[b];
  if (tid < 128) lcnt[tid] = 0;
  __syncthreads();
  for (int k = tid; k < m; k += 256) atomicAdd(&lcnt[part[p0 + k] & 127], 1);
  __syncthreads();
  if (tid < 128) lscan[tid] = lcnt[tid];
  __syncthreads();
  for (int d = 1; d < 128; d <<= 1) {
    int v = 0;
    if (tid < 128 && tid >= d) v = lscan[tid - d];
    __syncthreads();
    if (tid < 128) lscan[tid] += v;
    __syncthreads();
  }
  if (tid < 128) {
    int ex = lscan[tid] - lcnt[tid];
    lcur[tid] = ex;
    int n = (b << 7) + tid;
    if (n < Nn) offdeg[n] = make_int2(p0 + ex, lcnt[tid]);
  }
  __syncthreads();
  for (int k = tid; k < m; k += 256) {
    int pk = part[p0 + k];
    int pos = p0 + atomicAdd(&lcur[pk & 127], 1);   // LDS atomic
    csr[pos] = pk >> 7;
  }
}

// ---- standalone gemm for layers 1..3 (bf16 input) ----
__global__ __launch_bounds__(256, 4)
void gemm_qkvs(const short* __restrict__ Xin, const short* __restrict__ WT2,
               const float* __restrict__ bc,
               unsigned int* __restrict__ qout, unsigned int* __restrict__ kvp,
               unsigned int* __restrict__ xrout, int Nn) {
  __shared__ int4 smem4[528];
  gemm_body<0>((short(*)[132])smem4, (const void*)Xin, WT2, bc, qout, kvp, xrout, Nn,
               blockIdx.x * 32, threadIdx.x);
}

// ---------------- attention: one WAVE per node, 16 lanes per edge (R16 proven) ---

__global__ __launch_bounds__(256)
void attn_kernel(unsigned int* __restrict__ q_h, const uint4* __restrict__ kvq,
                 const uint4* __restrict__ xr4, const int2* __restrict__ offdeg,
                 const int* __restrict__ csr, const float* __restrict__ Wb, int Nn) {
  int wv = __builtin_amdgcn_readfirstlane(threadIdx.x >> 6);
  int i = blockIdx.x * 4 + wv;
  if (i >= Nn) return;
  const int l = threadIdx.x & 63;
  const int j = l & 15;      // lane within edge-group: dims 8j..8j+7
  const int g = l >> 4;      // edge group 0..3

  const float QS = 0.17677669529663687f * 1.4426950408889634f;  // 1/sqrt(32)*log2e
  uint4 qw = ((const uint4*)q_h)[(size_t)i * 16 + j];
  int2 od = offdeg[i];
  float q0 = bflo(qw.x) * QS, q1 = bfhi(qw.x) * QS;
  float q2 = bflo(qw.y) * QS, q3 = bfhi(qw.y) * QS;
  float q4 = bflo(qw.z) * QS, q5 = bfhi(qw.z) * QS;
  float q6 = bflo(qw.w) * QS, q7 = bfhi(qw.w) * QS;

  const int e0 = od.x;
  const int dg = od.y;
  const int eend = e0 + dg;

  float denA = 0.f, denB = 0.f;
  float aA[8] = {0.f, 0.f, 0.f, 0.f, 0.f, 0.f, 0.f, 0.f};
  float aB[8] = {0.f, 0.f, 0.f, 0.f, 0.f, 0.f, 0.f, 0.f};

  auto comp = [&](const uint4& kv, bool valid, float& den, float (&a)[8]) {
    floatx2 k0 = __builtin_amdgcn_cvt_pk_f32_fp8((int)kv.x, false);
    floatx2 v0 = __builtin_amdgcn_cvt_pk_f32_fp8((int)kv.x, true);
    floatx2 k1 = __builtin_amdgcn_cvt_pk_f32_fp8((int)kv.y, false);
    floatx2 v1 = __builtin_amdgcn_cvt_pk_f32_fp8((int)kv.y, true);
    floatx2 k2 = __builtin_amdgcn_cvt_pk_f32_fp8((int)kv.z, false);
    floatx2 v2 = __builtin_amdgcn_cvt_pk_f32_fp8((int)kv.z, true);
    floatx2 k3 = __builtin_amdgcn_cvt_pk_f32_fp8((int)kv.w, false);
    floatx2 v3 = __builtin_amdgcn_cvt_pk_f32_fp8((int)kv.w, true);
    float d = q0 * k0.x + q1 * k0.y + q2 * k1.x + q3 * k1.y
            + q4 * k2.x + q5 * k2.y + q6 * k3.x + q7 * k3.y;
    d = dpp_add<0xB1>(d);        // quad_perm xor1
    d = dpp_add<0x4E>(d);        // quad_perm xor2 -> head dot in every lane of quad
    float p = valid ? exp2f(d) : 0.f;
    den += p;
    a[0] += p * v0.x; a[1] += p * v0.y; a[2] += p * v1.x; a[3] += p * v1.y;
    a[4] += p * v2.x; a[5] += p * v2.y; a[6] += p * v3.x; a[7] += p * v3.y;
  };

  for (int e = e0; e < eend; e += 64) {
    const int rem = eend - e;
    const int take = (rem < 64) ? rem : 64;          // chunk edge count (uniform)
    int il = e + l; if (il >= eend) il = eend - 1;
    const int sv = csr[il];                          // one coalesced load / 64 edges

    for (int b = 0; b < take; b += 16) {             // 16 edges (4 batches) in flight
      uint4 kv0, kv1, kv2, kv3;
      bool p0 = false, p1 = false, p2 = false, p3 = false;
      const int c0 = b + g, c1 = b + 4 + g, c2 = b + 8 + g, c3 = b + 12 + g;
      {
        p0 = c0 < take;
        int s = __shfl(sv, p0 ? c0 : 0);
        kv0 = kvq[(unsigned)((s << 4) | j)];
      }
      if (b + 4 < take) {
        p1 = c1 < take;
        int s = __shfl(sv, p1 ? c1 : 0);
        kv1 = kvq[(unsigned)((s << 4) | j)];
      }
      if (b + 8 < take) {
        p2 = c2 < take;
        int s = __shfl(sv, p2 ? c2 : 0);
        kv2 = kvq[(unsigned)((s << 4) | j)];
      }
      if (b + 12 < take) {
        p3 = c3 < take;
        int s = __shfl(sv, p3 ? c3 : 0);
        kv3 = kvq[(unsigned)((s << 4) | j)];
      }
      comp(kv0, p0, denA, aA);
      if (b + 4 < take)  comp(kv1, p1, denB, aB);
      if (b + 8 < take)  comp(kv2, p2, denA, aA);
      if (b + 12 < take) comp(kv3, p3, denB, aB);
    }
  }

  // issue epilogue loads early so they overlap the shuffle-merge chain
  uint4 xw = xr4[(size_t)i * 16 + j];
  float4 wo0 = *(const float4*)&Wb[8 * j];
  float4 wo1 = *(const float4*)&Wb[8 * j + 4];
  float4 wx0 = *(const float4*)&Wb[128 + 8 * j];
  float4 wx1 = *(const float4*)&Wb[128 + 8 * j + 4];
  float4 wd0 = *(const float4*)&Wb[256 + 8 * j];
  float4 wd1 = *(const float4*)&Wb[256 + 8 * j + 4];

  float den = denA + denB;
  float a0 = aA[0] + aB[0], a1 = aA[1] + aB[1], a2 = aA[2] + aB[2], a3 = aA[3] + aB[3];
  float a4 = aA[4] + aB[4], a5 = aA[5] + aB[5], a6 = aA[6] + aB[6], a7 = aA[7] + aB[7];

  // merge the 4 edge-groups (per node only; amortized over deg)
  den += __shfl_xor(den, 16); den += __shfl_xor(den, 32);
  a0 += __shfl_xor(a0, 16); a0 += __shfl_xor(a0, 32);
  a1 += __shfl_xor(a1, 16); a1 += __shfl_xor(a1, 32);
  a2 += __shfl_xor(a2, 16); a2 += __shfl_xor(a2, 32);
  a3 += __shfl_xor(a3, 16); a3 += __shfl_xor(a3, 32);
  a4 += __shfl_xor(a4, 16); a4 += __shfl_xor(a4, 32);
  a5 += __shfl_xor(a5, 16); a5 += __shfl_xor(a5, 32);
  a6 += __shfl_xor(a6, 16); a6 += __shfl_xor(a6, 32);
  a7 += __shfl_xor(a7, 16); a7 += __shfl_xor(a7, 32);

  float inv = 1.f / (den + 1e-16f);
  float o0 = a0 * inv, o1 = a1 * inv, o2 = a2 * inv, o3 = a3 * inv;
  float o4 = a4 * inv, o5 = a5 * inv, o6 = a6 * inv, o7 = a7 * inv;

  float x0 = bflo(xw.x), x1 = bfhi(xw.x);
  float x2 = bflo(xw.y), x3 = bfhi(xw.y);
  float x4 = bflo(xw.z), x5 = bfhi(xw.z);
  float x6 = bflo(xw.w), x7 = bfhi(xw.w);

  float c = o0 * wo0.x + o1 * wo0.y + o2 * wo0.z + o3 * wo0.w
          + o4 * wo1.x + o5 * wo1.y + o6 * wo1.z + o7 * wo1.w
          + x0 * wx0.x + x1 * wx0.y + x2 * wx0.z + x3 * wx0.w
          + x4 * wx1.x + x5 * wx1.y + x6 * wx1.z + x7 * wx1.w
          + (o0 - x0) * wd0.x + (o1 - x1) * wd0.y + (o2 - x2) * wd0.z + (o3 - x3) * wd0.w
          + (o4 - x4) * wd1.x + (o5 - x5) * wd1.y + (o6 - x6) * wd1.z + (o7 - x7) * wd1.w;
  // sum over the 16 lanes of each group — pure DPP
  c = dpp_add<0xB1>(c);    // xor1
  c = dpp_add<0x4E>(c);    // xor2
  c = dpp_add<0x141>(c);   // row_half_mirror: crosses quad within 8
  c = dpp_add<0x140>(c);   // row_mirror: crosses 8 within 16
  float beta = 1.f / (1.f + __expf(-c));

  if (g == 0) {
    float h0 = fmaxf(beta * x0 + (1.f - beta) * o0, 0.f);
    float h1 = fmaxf(beta * x1 + (1.f - beta) * o1, 0.f);
    float h2 = fmaxf(beta * x2 + (1.f - beta) * o2, 0.f);
    float h3 = fmaxf(beta * x3 + (1.f - beta) * o3, 0.f);
    float h4 = fmaxf(beta * x4 + (1.f - beta) * o4, 0.f);
    float h5 = fmaxf(beta * x5 + (1.f - beta) * o5, 0.f);
    float h6 = fmaxf(beta * x6 + (1.f - beta) * o6, 0.f);
    float h7 = fmaxf(beta * x7 + (1.f - beta) * o7, 0.f);
    uint4 hw;
    hw.x = pk_bf16(h0, h1);
    hw.y = pk_bf16(h2, h3);
    hw.z = pk_bf16(h4, h5);
    hw.w = pk_bf16(h6, h7);
    ((uint4*)q_h)[(size_t)i * 16 + j] = hw;
  }
}

// ---------------- fused mean-pool + MLP ----------------

__global__ __launch_bounds__(128)
void poolmlp_kernel(const unsigned short* __restrict__ h, const int* __restrict__ goff,
                    const float* __restrict__ W1, const float* __restrict__ b1,
                    const float* __restrict__ W2, const float* __restrict__ b2,
                    const float* __restrict__ W3, const float* __restrict__ b3,
                    float* __restrict__ out) {
  int g = blockIdx.x;
  int t = threadIdx.x;
  int n0 = goff[g], cnt = goff[g + 1] - n0;
  float s = 0.f;
  for (int n = n0; n < n0 + cnt; ++n) s += bflo(h[(size_t)n * 128 + t]);
  __shared__ float gv[128];
  __shared__ float t1[64];
  __shared__ float t2[32];
  gv[t] = s / fmaxf((float)cnt, 1.0f);
  __syncthreads();
  if (t < 64) {
    float a = b1[t];
    for (int k = 0; k < 128; ++k) a += gv[k] * W1[k * 64 + t];
    t1[t] = fmaxf(a, 0.f);
  }
  __syncthreads();
  if (t < 32) {
    float a = b2[t];
    for (int k = 0; k < 64; ++k) a += t1[k] * W2[k * 32 + t];
    t2[t] = fmaxf(a, 0.f);
  }
  __syncthreads();
  if (t == 0) {
    float a = b3[0];
    for (int k = 0; k < 32; ++k) a += t2[k] * W3[k];
    out[g] = 1.f / (1.f + __expf(-a));
  }
}

// ---------------- launch ----------------

extern "C" void kernel_launch(void* const* d_in, const int* in_sizes, int n_in,
                              void* d_out, int out_size, void* d_ws, size_t ws_size,
                              hipStream_t stream) {
  const float* x = (const float*)d_in[0];
  const int* edge_index = (const int*)d_in[1];
  const int* batch = (const int*)d_in[2];
  const int N = in_sizes[0] / DH;
  const int E = in_sizes[1] / 2;
  const int G = out_size;
  const int* src = edge_index;
  const int* dst = edge_index + E;

  const float* in_Wq = (const float*)d_in[3];
  const float* in_bq = (const float*)d_in[4];
  const float* in_Wk = (const float*)d_in[5];
  const float* in_bk = (const float*)d_in[6];
  const float* in_Wv = (const float*)d_in[7];
  const float* in_bv = (const float*)d_in[8];
  const float* in_Ws = (const float*)d_in[9];
  const float* in_bs = (const float*)d_in[10];
  const float* in_Wbeta = (const float*)d_in[11];
  const float* blk_Wq = (const float*)d_in[12];
  const float* blk_bq = (const float*)d_in[13];
  const float* blk_Wk = (const float*)d_in[14];
  const float* blk_bk = (const float*)d_in[15];
  const float* blk_Wv = (const float*)d_in[16];
  const float* blk_bv = (const float*)d_in[17];
  const float* blk_Ws = (const float*)d_in[18];
  const float* blk_bs = (const float*)d_in[19];
  const float* blk_Wbeta = (const float*)d_in[20];

  // workspace carve (256B aligned)
  char* p = (char*)d_ws;
  auto take = [&](size_t bytes) { char* r = p; p += (bytes + 255) & ~(size_t)255; return r; };
  __hip_bfloat16* h0 = (__hip_bfloat16*)take((size_t)N * DH * 2);
  __hip_bfloat16* h1 = (__hip_bfloat16*)take((size_t)N * DH * 2);
  unsigned char* kvp = (unsigned char*)take((size_t)N * 256);
  unsigned short* xr = (unsigned short*)take((size_t)N * DH * 2);
  __hip_bfloat16* WT2 = (__hip_bfloat16*)take((size_t)4 * 512 * DH * 2);
  float* bcat = (float*)take((size_t)4 * 512 * 4);
  int2* offdeg = (int2*)take((size_t)N * 8);
  int* csr    = (int*)take((size_t)E * 4);
  int* part   = (int*)take((size_t)E * 4);
  int* hist   = (int*)take((size_t)NB * NBK * 4);
  int* total  = (int*)take(NBK * 4);
  int* tstart = (int*)take(NBK * 4);
  int* goff   = (int*)take((size_t)(G + 1) * 4);
  (void)n_in;
  if ((size_t)(p - (char*)d_ws) > ws_size) return;

  const int NBUCK = (N + 127) >> 7;
  const int chunk = (E + NB - 1) / NB;
  const int gblocks = (G + 256) / 256;

  // ---- MEGA 1: csr_p1 | pack_w(all layers) | goff ----
  fused_pre<<<NB + 260 + gblocks, 256, 0, stream>>>(
      dst, hist, E, chunk, batch, goff, N, G,
      in_Wq, in_Wk, in_Wv, in_Ws, in_bq, in_bk, in_bv, in_bs,
      blk_Wq, blk_Wk, blk_Wv, blk_Ws, blk_bq, blk_bk, blk_bv, blk_bs,
      WT2, bcat);

  csr_p2<<<NBK / 4, 256, 0, stream>>>(hist, total);
  scan_tstart<<<1, 1024, 0, stream>>>(total, tstart);

  // ---- MEGA 2: csr_p3 (first NB blocks) | gemm layer-0 ----
  fused_g0p3<<<NB + (N + 31) / 32, 256, 0, stream>>>(
      (const void*)x, (const short*)WT2, bcat,
      (unsigned int*)h1, (unsigned int*)kvp, (unsigned int*)xr, N,
      src, dst, hist, tstart, part, E, chunk);

  csr_p4<<<NBUCK, 256, 0, stream>>>(part, tstart, total, offdeg, csr, N);

  // layer 0 attention (q in h1, h -> h1)
  attn_kernel<<<(N + 3) / 4, 256, 0, stream>>>((unsigned int*)h1, (const uint4*)kvp,
      (const uint4*)xr, offdeg, csr, in_Wbeta, N);

  for (int l = 1; l < 4; ++l) {
    const float* Wb = blk_Wbeta + (size_t)(l - 1) * 3 * DH;
    const short* WT2l = (const short*)WT2 + (size_t)l * 65536;
    const float* bcl = bcat + (size_t)l * 512;
    __hip_bfloat16* hin  = (l & 1) ? h1 : h0;   // layer1 reads h1, writes q to h0; etc.
    __hip_bfloat16* qbuf = (l & 1) ? h0 : h1;
    gemm_qkvs<<<(N + 31) / 32, 256, 0, stream>>>((const short*)hin, WT2l, bcl,
        (unsigned int*)qbuf, (unsigned int*)kvp, (unsigned int*)xr, N);
    attn_kernel<<<(N + 3) / 4, 256, 0, stream>>>((unsigned int*)qbuf, (const uint4*)kvp,
        (const uint4*)xr, offdeg, csr, Wb, N);
  }

  // after 4 layers h lives in h0 (layers wrote h1,h0,h1,h0)
  poolmlp_kernel<<<G, 128, 0, stream>>>((const unsigned short*)h0, goff,
      (const float*)d_in[21], (const float*)d_in[22],
      (const float*)d_in[23], (const float*)d_in[24],
      (const float*)d_in[25], (const float*)d_in[26],
      (float*)d_out);
}